// Round 2
// baseline (125.590 us; speedup 1.0000x reference)
//
#include <hip/hip_runtime.h>
#include <hip/hip_bf16.h>
#include <math.h>

// BoxE scorer:
//   y: (2048, 256) f32   -> boxes: mn = y[:, :128], delta = softplus(y[:, 128:])
//   x: (1024, 128) f32   -> points
//   out[m][n] = -|| per_dim(x[m], box[n]) ||_2,  shape (1024, 2048) f32
//
// per_dim (k-th):
//   center = mn + delta/2 ; dp1 = delta+1 ; l1 = |x - center|
//   inside (|x-center| <= delta/2): l1 / (dp1 + 1e-10)
//   outside: l1*dp1 - c2,  c2 = delta/2*(delta - 1/(delta+1e-10))
//
// Strategy: prep kernel precomputes per-(n,k) params {center, hd, inv_dp1, dp1}
// (float4, layout [k][n] for coalesced lane-across-n loads) + c2[k][n], and
// xT[k][m]. Main kernel: BM=32 x BN=128 tile / 256-thread block, TM=8 rows per
// thread from LDS (uniform broadcast), TN=2 boxes per lane.

#define BM 32
#define BN 128
#define TM 8

__global__ void boxe_prep(const float* __restrict__ y, const float* __restrict__ x,
                          float4* __restrict__ p4, float* __restrict__ c2,
                          float* __restrict__ xT)
{
    int idx = blockIdx.x * blockDim.x + threadIdx.x;
    if (idx < 2048 * 128) {
        // idx = k*2048 + n  (n fastest -> coalesced writes)
        int n = idx & 2047;
        int k = idx >> 11;
        float mn = y[n * 256 + k];
        float dv = y[n * 256 + 128 + k];
        // stable softplus: max(v,0) + log1p(exp(-|v|))
        float delta = fmaxf(dv, 0.0f) + log1pf(expf(-fabsf(dv)));
        float hd = 0.5f * delta;
        float center = mn + hd;
        float dp1 = delta + 1.0f;
        float inv = 1.0f / (dp1 + 1e-10f);
        float cc = hd * (delta - 1.0f / (delta + 1e-10f));
        p4[idx] = make_float4(center, hd, inv, dp1);
        c2[idx] = cc;
    } else {
        int j = idx - 2048 * 128;
        if (j < 1024 * 128) {
            // j = k*1024 + m  (m fastest -> coalesced writes)
            int m = j & 1023;
            int k = j >> 10;
            xT[j] = x[m * 128 + k];
        }
    }
}

__global__ __launch_bounds__(256) void boxe_main(
    const float4* __restrict__ p4, const float* __restrict__ c2,
    const float* __restrict__ xT, float* __restrict__ out)
{
    __shared__ float xtile[128][BM];   // 16 KiB, [k][m]

    const int tid  = threadIdx.x;
    const int lane = tid & 63;
    const int wave = tid >> 6;
    const int m0   = blockIdx.y * BM;
    const int n0   = blockIdx.x * BN;

    // Stage x tile: 128 k x 32 m = 4096 floats, 16 per thread.
    // Consecutive tids -> consecutive m at fixed k (two 128B segments/wave).
#pragma unroll
    for (int i = 0; i < (128 * BM) / 256; ++i) {
        int idx = i * 256 + tid;
        int k = idx >> 5;
        int m = idx & (BM - 1);
        xtile[k][m] = xT[k * 1024 + m0 + m];
    }
    __syncthreads();

    float acc0[TM], acc1[TM];
#pragma unroll
    for (int r = 0; r < TM; ++r) { acc0[r] = 0.0f; acc1[r] = 0.0f; }

    const int nA = n0 + lane;        // box A for this lane
    const int nB = n0 + 64 + lane;   // box B for this lane
    const int mw = wave * TM;        // this wave's m-offset within tile

#pragma unroll 4
    for (int k = 0; k < 128; ++k) {
        float4 pA = p4[k * 2048 + nA];   // {center, hd, inv_dp1, dp1} coalesced
        float4 pB = p4[k * 2048 + nB];
        float cA = c2[k * 2048 + nA];
        float cB = c2[k * 2048 + nB];
#pragma unroll
        for (int r = 0; r < TM; ++r) {
            float xv = xtile[k][mw + r];          // uniform addr -> LDS broadcast
            float lA = fabsf(xv - pA.x);
            float vA = (lA <= pA.y) ? (lA * pA.z) : fmaf(lA, pA.w, -cA);
            acc0[r] = fmaf(vA, vA, acc0[r]);
            float lB = fabsf(xv - pB.x);
            float vB = (lB <= pB.y) ? (lB * pB.z) : fmaf(lB, pB.w, -cB);
            acc1[r] = fmaf(vB, vB, acc1[r]);
        }
    }

#pragma unroll
    for (int r = 0; r < TM; ++r) {
        int m = m0 + mw + r;
        out[m * 2048 + nA] = -sqrtf(acc0[r]);
        out[m * 2048 + nB] = -sqrtf(acc1[r]);
    }
}

extern "C" void kernel_launch(void* const* d_in, const int* in_sizes, int n_in,
                              void* d_out, int out_size, void* d_ws, size_t ws_size,
                              hipStream_t stream) {
    const float* y = (const float*)d_in[0];   // 2048*256
    const float* x = (const float*)d_in[1];   // 1024*128
    float* out = (float*)d_out;               // 1024*2048

    char* ws = (char*)d_ws;
    float4* p4 = (float4*)ws;                         // 4 MiB: [128][2048] float4
    float*  c2 = (float*)(ws + 4u * 1024 * 1024);     // 1 MiB: [128][2048]
    float*  xT = (float*)(ws + 5u * 1024 * 1024);     // 512 KiB: [128][1024]

    int total = 2048 * 128 + 1024 * 128;              // 393216 threads
    hipLaunchKernelGGL(boxe_prep, dim3(total / 256), dim3(256), 0, stream,
                       y, x, p4, c2, xT);

    dim3 grid(2048 / BN, 1024 / BM);                  // (16, 32) = 512 blocks
    hipLaunchKernelGGL(boxe_main, grid, dim3(256), 0, stream,
                       p4, c2, xT, out);
}

// Round 4
// 117.939 us; speedup vs baseline: 1.0649x; 1.0649x over previous
//
#include <hip/hip_runtime.h>
#include <hip/hip_bf16.h>
#include <math.h>

// BoxE scorer:
//   y: (2048, 256) f32 -> boxes: mn = y[:, :128], delta = softplus(y[:, 128:])
//   x: (1024, 128) f32 -> points
//   out[m][n] = -|| per_dim(x[m], box[n]) ||_2, shape (1024, 2048) f32
//
// per_dim (k-th):
//   center = mn + delta/2 ; dp1 = delta+1 ; l1 = |x - center|
//   inside (|x-center| <= delta/2): l1 / (dp1 + 1e-10)
//   outside: l1*dp1 - c2,  c2 = delta/2*(delta - 1/(delta+1e-10))
//
// R3: occupancy fix. Grid 512->1024 blocks (BN 128->64, TN 2->1): 4 blocks/CU,
// 16 waves/CU. Params packed to one float4 {center, hd, inv, c2}; dp1 = 2*hd+1
// recomputed in-loop (exact: hd = delta/2 is an exact f32 halving).

#define BM 32
#define BN 64
#define TM 8

__global__ void boxe_prep(const float* __restrict__ y, const float* __restrict__ x,
                          float4* __restrict__ p4, float* __restrict__ xT)
{
    int idx = blockIdx.x * blockDim.x + threadIdx.x;
    if (idx < 2048 * 128) {
        // idx = k*2048 + n (n fastest -> coalesced writes of p4)
        int n = idx & 2047;
        int k = idx >> 11;
        float mn = y[n * 256 + k];
        float dv = y[n * 256 + 128 + k];
        // stable softplus: max(v,0) + log1p(exp(-|v|))
        float delta = fmaxf(dv, 0.0f) + log1pf(expf(-fabsf(dv)));
        float hd = 0.5f * delta;
        float center = mn + hd;
        float dp1 = delta + 1.0f;
        float inv = 1.0f / (dp1 + 1e-10f);
        float cc = hd * (delta - 1.0f / (delta + 1e-10f));
        p4[idx] = make_float4(center, hd, inv, cc);
    } else {
        int j = idx - 2048 * 128;
        if (j < 1024 * 128) {
            // j = k*1024 + m (m fastest -> coalesced writes of xT)
            int m = j & 1023;
            int k = j >> 10;
            xT[j] = x[m * 128 + k];
        }
    }
}

__global__ __launch_bounds__(256) void boxe_main(
    const float4* __restrict__ p4, const float* __restrict__ xT,
    float* __restrict__ out)
{
    __shared__ float xtile[128][BM];   // 16 KiB, [k][m]

    const int tid  = threadIdx.x;
    const int lane = tid & 63;
    const int wave = tid >> 6;
    const int m0   = blockIdx.y * BM;
    const int n0   = blockIdx.x * BN;

    // Stage x tile: 128 k x 32 m = 4096 floats, 16 per thread.
#pragma unroll
    for (int i = 0; i < (128 * BM) / 256; ++i) {
        int idx = i * 256 + tid;
        int k = idx >> 5;
        int m = idx & (BM - 1);
        xtile[k][m] = xT[k * 1024 + m0 + m];
    }
    __syncthreads();

    float acc[TM];
#pragma unroll
    for (int r = 0; r < TM; ++r) acc[r] = 0.0f;

    const int n  = n0 + lane;     // one box per lane, coalesced float4 loads
    const int mw = wave * TM;     // this wave's m-offset within tile

#pragma unroll 4
    for (int k = 0; k < 128; ++k) {
        float4 p = p4[k * 2048 + n];              // {center, hd, inv, c2}
        float dp1 = fmaf(2.0f, p.y, 1.0f);        // delta+1, exact
#pragma unroll
        for (int r = 0; r < TM; ++r) {
            float xv = xtile[k][mw + r];          // uniform addr -> LDS broadcast
            float l = fabsf(xv - p.x);
            float v = (l <= p.y) ? (l * p.z) : fmaf(l, dp1, -p.w);
            acc[r] = fmaf(v, v, acc[r]);
        }
    }

#pragma unroll
    for (int r = 0; r < TM; ++r) {
        int m = m0 + mw + r;
        out[m * 2048 + n] = -sqrtf(acc[r]);
    }
}

extern "C" void kernel_launch(void* const* d_in, const int* in_sizes, int n_in,
                              void* d_out, int out_size, void* d_ws, size_t ws_size,
                              hipStream_t stream) {
    const float* y = (const float*)d_in[0];   // 2048*256
    const float* x = (const float*)d_in[1];   // 1024*128
    float* out = (float*)d_out;               // 1024*2048

    char* ws = (char*)d_ws;
    float4* p4 = (float4*)ws;                         // 4 MiB: [128][2048] float4
    float*  xT = (float*)(ws + 4u * 1024 * 1024);     // 512 KiB: [128][1024]

    int total = 2048 * 128 + 1024 * 128;              // 393216 threads
    hipLaunchKernelGGL(boxe_prep, dim3(total / 256), dim3(256), 0, stream,
                       y, x, p4, xT);

    dim3 grid(2048 / BN, 1024 / BM);                  // (32, 32) = 1024 blocks
    hipLaunchKernelGGL(boxe_main, grid, dim3(256), 0, stream,
                       p4, xT, out);
}